// Round 4
// baseline (324.014 us; speedup 1.0000x reference)
//
#include <hip/hip_runtime.h>
#include <hip/hip_bf16.h>

typedef __hip_bfloat16 bf16;
typedef __attribute__((ext_vector_type(8))) short bf16x8;
typedef __attribute__((ext_vector_type(4))) float f32x4;

#define N_LOC 4096

__device__ __forceinline__ bf16 to_bf16(float f) { return __float2bfloat16(f); }

// async global->LDS DMA, 16B per lane; LDS dest = wave-uniform base + lane*16
__device__ __forceinline__ void dma16(const bf16* g, bf16* l) {
  __builtin_amdgcn_global_load_lds((const __attribute__((address_space(1))) unsigned int*)g,
                                   (__attribute__((address_space(3))) unsigned int*)l, 16, 0, 0);
}

// ---------------- prep: f32->bf16 convert (Q,K,V,Wo) + W transpose-pack, one launch ----------------
// blocks 0..3327: convert 8 floats/thread. blocks 3328..3711: pack_wt tiles.
__global__ __launch_bounds__(256) void prep(const float* __restrict__ Q, const float* __restrict__ K,
                                            const float* __restrict__ V, const float* __restrict__ Wo,
                                            const float* __restrict__ Wq, const float* __restrict__ Wk,
                                            const float* __restrict__ Wv,
                                            bf16* __restrict__ Qb, bf16* __restrict__ Kb,
                                            bf16* __restrict__ Vb, bf16* __restrict__ Wob,
                                            bf16* __restrict__ oq, bf16* __restrict__ ok,
                                            bf16* __restrict__ ov) {
  int b = blockIdx.x;
  if (b < 3328) {
    long i = ((long)b * 256 + threadIdx.x) * 8;
    const float* src; bf16* dst; long off;
    if (i < 2097152)      { src = Q;  dst = Qb;  off = i; }
    else if (i < 4194304) { src = K;  dst = Kb;  off = i - 2097152; }
    else if (i < 6291456) { src = V;  dst = Vb;  off = i - 4194304; }
    else                  { src = Wo; dst = Wob; off = i - 6291456; }
    float4 a = *(const float4*)&src[off];
    float4 c = *(const float4*)&src[off + 4];
    union { bf16 h[8]; bf16x8 v; } u;
    u.h[0] = to_bf16(a.x); u.h[1] = to_bf16(a.y); u.h[2] = to_bf16(a.z); u.h[3] = to_bf16(a.w);
    u.h[4] = to_bf16(c.x); u.h[5] = to_bf16(c.y); u.h[6] = to_bf16(c.z); u.h[7] = to_bf16(c.w);
    *(bf16x8*)&dst[off] = u.v;
    return;
  }
  int t = b - 3328;                       // 0..383 = (x 0..7, y 0..15, z 0..2)
  int z = t >> 7, rem = t & 127;
  int xb = rem & 7, y = rem >> 3;
  const float* W = (z == 0) ? Wq : (z == 1) ? Wk : Wv;
  bf16* out = (z == 0) ? oq : (z == 1) ? ok : ov;
  int DH = (z == 2) ? 256 : 128;
  int nt = DH >> 6;
  if (y >= 4 * nt) return;
  int h = y / nt, tt = y - h * nt;
  int d0 = xb * 64, t0 = tt * 64;
  __shared__ float tile[64][65];
  for (int i = threadIdx.x; i < 4096; i += 256) {
    int r = i >> 6, c = i & 63;
    tile[r][c] = W[((size_t)h * 512 + d0 + r) * DH + t0 + c];
  }
  __syncthreads();
  for (int i = threadIdx.x; i < 4096; i += 256) {
    int tr = i >> 6, d = i & 63;
    out[((size_t)(h * DH + t0 + tr)) * 512 + d0 + d] = to_bf16(tile[d][tr]);
  }
}

// ---------------- batched projection GEMM (Q,K,V) ----------------
// blocks 0..511: qb = Qb@WqT; 512..1023: kb = Kb@WkT; 1024..2047: vT = (Vb@WvT)^T
__global__ __launch_bounds__(256) void proj_gemm(const bf16* __restrict__ Qb, const bf16* __restrict__ Wqt,
                                                 const bf16* __restrict__ Kb, const bf16* __restrict__ Wkt,
                                                 const bf16* __restrict__ Vb, const bf16* __restrict__ Wvt,
                                                 bf16* __restrict__ qb, bf16* __restrict__ kb,
                                                 bf16* __restrict__ vT) {
  const int LD = 72;
  __shared__ bf16 As[64 * LD];
  __shared__ bf16 Bs[64 * LD];
  int b = blockIdx.x;
  const bf16 *A, *Bt;
  bf16* Cout;
  int N, m0, n0, tr;
  if (b < 512)       { A = Qb; Bt = Wqt; Cout = qb; N = 512;  m0 = (b >> 3) * 64; n0 = (b & 7) * 64;  tr = 0; }
  else if (b < 1024) { b -= 512;  A = Kb; Bt = Wkt; Cout = kb; N = 512;  m0 = (b >> 3) * 64; n0 = (b & 7) * 64;  tr = 0; }
  else               { b -= 1024; A = Vb; Bt = Wvt; Cout = vT; N = 1024; m0 = (b >> 4) * 64; n0 = (b & 15) * 64; tr = 1; }

  int tid = threadIdx.x;
  int lane = tid & 63, w = tid >> 6;
  int quad = lane >> 4, l16 = lane & 15;
  int wm = (w >> 1) * 32, wn = (w & 1) * 32;

  f32x4 acc[2][2] = {};
  for (int k0 = 0; k0 < 512; k0 += 64) {
    for (int i = tid; i < 64 * 8; i += 256) {
      int r = i >> 3, c = (i & 7) * 8;
      *(bf16x8*)&As[r * LD + c] = *(const bf16x8*)&A[(size_t)(m0 + r) * 512 + k0 + c];
      *(bf16x8*)&Bs[r * LD + c] = *(const bf16x8*)&Bt[(size_t)(n0 + r) * 512 + k0 + c];
    }
    __syncthreads();
#pragma unroll
    for (int kk = 0; kk < 2; kk++) {
      bf16x8 af[2], bfr[2];
#pragma unroll
      for (int i = 0; i < 2; i++)
        af[i] = *(const bf16x8*)&As[(wm + i * 16 + l16) * LD + kk * 32 + quad * 8];
#pragma unroll
      for (int j = 0; j < 2; j++)
        bfr[j] = *(const bf16x8*)&Bs[(wn + j * 16 + l16) * LD + kk * 32 + quad * 8];
#pragma unroll
      for (int i = 0; i < 2; i++)
#pragma unroll
        for (int j = 0; j < 2; j++)
          acc[i][j] = __builtin_amdgcn_mfma_f32_16x16x32_bf16(af[i], bfr[j], acc[i][j], 0, 0, 0);
    }
    __syncthreads();
  }
  if (!tr) {
#pragma unroll
    for (int i = 0; i < 2; i++)
#pragma unroll
      for (int j = 0; j < 2; j++)
#pragma unroll
        for (int r = 0; r < 4; r++)
          Cout[(size_t)(m0 + wm + i * 16 + quad * 4 + r) * N + n0 + wn + j * 16 + l16] =
              to_bf16(acc[i][j][r]);
  } else {
    // transpose in LDS (reuse As), then vectorized writes of vT rows
    bf16* tb = As;  // [col 64][row 64], LD 72
#pragma unroll
    for (int i = 0; i < 2; i++)
#pragma unroll
      for (int j = 0; j < 2; j++)
#pragma unroll
        for (int r = 0; r < 4; r++)
          tb[(wn + j * 16 + l16) * LD + wm + i * 16 + quad * 4 + r] = to_bf16(acc[i][j][r]);
    __syncthreads();
    for (int idx = tid; idx < 512; idx += 256) {
      int c = idx >> 3, s = idx & 7;
      *(bf16x8*)&vT[(size_t)(n0 + c) * 4096 + m0 + s * 8] = *(const bf16x8*)&tb[c * LD + s * 8];
    }
  }
}

// ---------------- fused attention ----------------
// qb,kb: [N][512]; vT: [1024][N]; x: [N][1024]
// 256 threads = 4 waves; 64 queries/block; 64-key iters.
//   S : wave (qh=w&1, kh=w>>1) computes 32q x 32key via 2x2 16x16 tiles (q in regs)
//   PV: wave owns ALL 4 q-tiles x dv range w*64..w*64+63 (4x4 tiles, ratio 32 FLOP/LDS-B
//       vs round-3's 21.3 -> 96 instead of 128 ds_read_b128 per block-iter)
//   L : wave w accumulates the ones-column for q-tile w (balanced, 2 MFMA/iter)
// kt/vt XOR-swizzled, filled by global_load_lds DMA (granule G of row r at G^(r&7)).
__global__ __launch_bounds__(256, 2) void attn(const bf16* __restrict__ qb,
                                               const bf16* __restrict__ kb,
                                               const bf16* __restrict__ vT,
                                               bf16* __restrict__ x) {
  __shared__ __align__(16) bf16 kt[64 * 128];   // [key][dk] swizzled, 16 KB
  __shared__ __align__(16) bf16 vt[256 * 64];   // [dv][key] swizzled, 32 KB
  __shared__ __align__(16) bf16 pt[64 * 72];    // [q][key], padded
  __shared__ float Lrow[64];

  const int head = blockIdx.x & 3;              // XCD-local head
  const int q0 = (blockIdx.x >> 2) * 64;
  const int tid = threadIdx.x;
  const int lane = tid & 63, w = tid >> 6;      // 4 waves
  const int quad = lane >> 4, l16 = lane & 15;
  const int qh = w & 1, kh = w >> 1;

  // all-ones B-fragment: B[n][k]=(n==0) -> D[q][0] = sum_k P[q][k]
  bf16x8 onesf;
  {
    union { bf16 h[8]; bf16x8 v; } u;
    bf16 one = to_bf16(1.0f), zero = to_bf16(0.0f);
#pragma unroll
    for (int j = 0; j < 8; j++) u.h[j] = (l16 == 0) ? one : zero;
    onesf = u.v;
  }

  // preload q fragments: rows qh*32 + i*16 (A-layout m=l16, k=quad*8+j)
  bf16x8 qf[2][4];
#pragma unroll
  for (int i = 0; i < 2; i++) {
    const bf16* qrow = &qb[(size_t)(q0 + qh * 32 + i * 16 + l16) * 512 + head * 128];
#pragma unroll
    for (int kk = 0; kk < 4; kk++) qf[i][kk] = *(const bf16x8*)&qrow[kk * 32 + quad * 8];
  }

  f32x4 oacc[4][4] = {};
  f32x4 oL = {};
  const float scale = 1.0f / 64.0f;  // 1/sqrt(4096)

  for (int key0 = 0; key0 < N_LOC; key0 += 64) {
    // ---- DMA staging: kt chunks 4w..4w+3, vt chunks 8w..8w+7 (1 KB each) ----
#pragma unroll
    for (int t = 0; t < 4; t++) {
      int j = 4 * w + t;
      int r = 4 * j + (lane >> 4);              // key row 0..63
      int p = lane & 15;
      int G = (p & 8) | ((p ^ r) & 7);
      dma16(&kb[(size_t)(key0 + r) * 512 + head * 128 + G * 8], &kt[j * 512]);
    }
#pragma unroll
    for (int t = 0; t < 8; t++) {
      int j = 8 * w + t;
      int r = 8 * j + (lane >> 3);              // dv row 0..255
      int p = lane & 7;
      int G = (p ^ r) & 7;
      dma16(&vT[(size_t)(head * 256 + r) * 4096 + key0 + G * 8], &vt[j * 512]);
    }
    __syncthreads();  // drains DMA + joins waves

    // ---- S: wave computes q rows qh*32..+31  x  keys kh*32..+31 ----
    f32x4 sacc[2][2] = {};
#pragma unroll
    for (int kk = 0; kk < 4; kk++) {
#pragma unroll
      for (int t = 0; t < 2; t++) {
        int R = kh * 32 + t * 16 + l16;
        int G = kk * 4 + quad;
        bf16x8 kf = *(const bf16x8*)&kt[R * 128 + (((G ^ R) & 7) | (G & 8)) * 8];
#pragma unroll
        for (int i = 0; i < 2; i++)
          sacc[i][t] = __builtin_amdgcn_mfma_f32_16x16x32_bf16(qf[i][kk], kf, sacc[i][t], 0, 0, 0);
      }
    }
#pragma unroll
    for (int i = 0; i < 2; i++)
#pragma unroll
      for (int t = 0; t < 2; t++)
#pragma unroll
        for (int r = 0; r < 4; r++)
          pt[(qh * 32 + i * 16 + quad * 4 + r) * 72 + kh * 32 + t * 16 + l16] =
              to_bf16(__expf(sacc[i][t][r] * scale));
    __syncthreads();

    // ---- PV: wave owns all 4 q-tiles x dv cols w*64..+63 ----
#pragma unroll
    for (int kk = 0; kk < 2; kk++) {
      bf16x8 pf[4];
#pragma unroll
      for (int i = 0; i < 4; i++)
        pf[i] = *(const bf16x8*)&pt[(i * 16 + l16) * 72 + kk * 32 + quad * 8];
      oL = __builtin_amdgcn_mfma_f32_16x16x32_bf16(pf[w], onesf, oL, 0, 0, 0);
#pragma unroll
      for (int c = 0; c < 4; c++) {
        int R = w * 64 + c * 16 + l16;
        int G = kk * 4 + quad;
        bf16x8 vf = *(const bf16x8*)&vt[R * 64 + ((G ^ R) & 7) * 8];
#pragma unroll
        for (int i = 0; i < 4; i++)
          oacc[i][c] = __builtin_amdgcn_mfma_f32_16x16x32_bf16(pf[i], vf, oacc[i][c], 0, 0, 0);
      }
    }
    __syncthreads();
  }

  // L for q-tile w at lanes l16==0 (C-layout col 0)
  if (l16 == 0) {
#pragma unroll
    for (int r = 0; r < 4; r++) Lrow[w * 16 + quad * 4 + r] = oL[r];
  }
  __syncthreads();

  // normalize + write x[n][head*256 + w*64 + ...]
#pragma unroll
  for (int i = 0; i < 4; i++)
#pragma unroll
    for (int c = 0; c < 4; c++)
#pragma unroll
      for (int r = 0; r < 4; r++) {
        int row = i * 16 + quad * 4 + r;
        float v = oacc[i][c][r] / Lrow[row];
        x[(size_t)(q0 + row) * 1024 + head * 256 + w * 64 + c * 16 + l16] = to_bf16(v);
      }
}

// ---------------- output GEMM: out[M][512] = x[M][1024] @ Wob[512][1024]^T, fp32 out ----------------
__global__ __launch_bounds__(256) void out_gemm(const bf16* __restrict__ A,
                                                const bf16* __restrict__ Bt,
                                                float* __restrict__ C) {
  const int LD = 72;
  __shared__ bf16 As[64 * LD];
  __shared__ bf16 Bs[64 * LD];
  int tid = threadIdx.x;
  int lane = tid & 63, w = tid >> 6;
  int quad = lane >> 4, l16 = lane & 15;
  int wm = (w >> 1) * 32, wn = (w & 1) * 32;
  int m0 = blockIdx.x * 64, n0 = blockIdx.y * 64;

  f32x4 acc[2][2] = {};
  for (int k0 = 0; k0 < 1024; k0 += 64) {
    for (int i = tid; i < 64 * 8; i += 256) {
      int r = i >> 3, c = (i & 7) * 8;
      *(bf16x8*)&As[r * LD + c] = *(const bf16x8*)&A[(size_t)(m0 + r) * 1024 + k0 + c];
      *(bf16x8*)&Bs[r * LD + c] = *(const bf16x8*)&Bt[(size_t)(n0 + r) * 1024 + k0 + c];
    }
    __syncthreads();
#pragma unroll
    for (int kk = 0; kk < 2; kk++) {
      bf16x8 af[2], bfr[2];
#pragma unroll
      for (int i = 0; i < 2; i++)
        af[i] = *(const bf16x8*)&As[(wm + i * 16 + l16) * LD + kk * 32 + quad * 8];
#pragma unroll
      for (int j = 0; j < 2; j++)
        bfr[j] = *(const bf16x8*)&Bs[(wn + j * 16 + l16) * LD + kk * 32 + quad * 8];
#pragma unroll
      for (int i = 0; i < 2; i++)
#pragma unroll
        for (int j = 0; j < 2; j++)
          acc[i][j] = __builtin_amdgcn_mfma_f32_16x16x32_bf16(af[i], bfr[j], acc[i][j], 0, 0, 0);
    }
    __syncthreads();
  }
#pragma unroll
  for (int i = 0; i < 2; i++)
#pragma unroll
    for (int j = 0; j < 2; j++)
#pragma unroll
      for (int r = 0; r < 4; r++)
        C[(size_t)(m0 + wm + i * 16 + quad * 4 + r) * 512 + n0 + wn + j * 16 + l16] =
            acc[i][j][r];
}

// ---------------- launch ----------------
extern "C" void kernel_launch(void* const* d_in, const int* in_sizes, int n_in,
                              void* d_out, int out_size, void* d_ws, size_t ws_size,
                              hipStream_t stream) {
  const float* Q  = (const float*)d_in[0];
  const float* Km = (const float*)d_in[1];
  const float* V  = (const float*)d_in[2];
  const float* Wq = (const float*)d_in[3];
  const float* Wk = (const float*)d_in[4];
  const float* Wv = (const float*)d_in[5];
  const float* Wo = (const float*)d_in[6];
  float* out = (float*)d_out;

  bf16* ws  = (bf16*)d_ws;
  bf16* Qb  = ws;                 // 4096x512
  bf16* Kb  = Qb + 2097152;
  bf16* Vb  = Kb + 2097152;
  bf16* Wqt = Vb + 2097152;       // 512x512  (Bt)
  bf16* Wkt = Wqt + 262144;
  bf16* Wvt = Wkt + 262144;       // 1024x512 (Bt)
  bf16* Wob = Wvt + 524288;       // 512x1024 (Bt = Wo as-is)
  bf16* qb  = Wob + 524288;       // 4096x512
  bf16* kb  = qb + 2097152;
  bf16* vT  = kb + 2097152;       // 1024x4096
  bf16* x   = vT + 4194304;       // 4096x1024

  prep<<<3712, 256, 0, stream>>>(Q, Km, V, Wo, Wq, Wk, Wv, Qb, Kb, Vb, Wob, Wqt, Wkt, Wvt);
  proj_gemm<<<2048, 256, 0, stream>>>(Qb, Wqt, Kb, Wkt, Vb, Wvt, qb, kb, vT);
  attn<<<256, 256, 0, stream>>>(qb, kb, vT, x);
  out_gemm<<<dim3(64, 8), 256, 0, stream>>>(x, Wob, out);
}

// Round 5
// 300.317 us; speedup vs baseline: 1.0789x; 1.0789x over previous
//
#include <hip/hip_runtime.h>
#include <hip/hip_bf16.h>

typedef __hip_bfloat16 bf16;
typedef __attribute__((ext_vector_type(8))) short bf16x8;
typedef __attribute__((ext_vector_type(4))) float f32x4;

#define N_LOC 4096

__device__ __forceinline__ bf16 to_bf16(float f) { return __float2bfloat16(f); }

// ---------------- prep: f32->bf16 convert (Q,K,V,Wo) + W transpose-pack, one launch ----------------
__global__ __launch_bounds__(256) void prep(const float* __restrict__ Q, const float* __restrict__ K,
                                            const float* __restrict__ V, const float* __restrict__ Wo,
                                            const float* __restrict__ Wq, const float* __restrict__ Wk,
                                            const float* __restrict__ Wv,
                                            bf16* __restrict__ Qb, bf16* __restrict__ Kb,
                                            bf16* __restrict__ Vb, bf16* __restrict__ Wob,
                                            bf16* __restrict__ oq, bf16* __restrict__ ok,
                                            bf16* __restrict__ ov) {
  int b = blockIdx.x;
  if (b < 3328) {
    long i = ((long)b * 256 + threadIdx.x) * 8;
    const float* src; bf16* dst; long off;
    if (i < 2097152)      { src = Q;  dst = Qb;  off = i; }
    else if (i < 4194304) { src = K;  dst = Kb;  off = i - 2097152; }
    else if (i < 6291456) { src = V;  dst = Vb;  off = i - 4194304; }
    else                  { src = Wo; dst = Wob; off = i - 6291456; }
    float4 a = *(const float4*)&src[off];
    float4 c = *(const float4*)&src[off + 4];
    union { bf16 h[8]; bf16x8 v; } u;
    u.h[0] = to_bf16(a.x); u.h[1] = to_bf16(a.y); u.h[2] = to_bf16(a.z); u.h[3] = to_bf16(a.w);
    u.h[4] = to_bf16(c.x); u.h[5] = to_bf16(c.y); u.h[6] = to_bf16(c.z); u.h[7] = to_bf16(c.w);
    *(bf16x8*)&dst[off] = u.v;
    return;
  }
  int t = b - 3328;
  int z = t >> 7, rem = t & 127;
  int xb = rem & 7, y = rem >> 3;
  const float* W = (z == 0) ? Wq : (z == 1) ? Wk : Wv;
  bf16* out = (z == 0) ? oq : (z == 1) ? ok : ov;
  int DH = (z == 2) ? 256 : 128;
  int nt = DH >> 6;
  if (y >= 4 * nt) return;
  int h = y / nt, tt = y - h * nt;
  int d0 = xb * 64, t0 = tt * 64;
  __shared__ float tile[64][65];
  for (int i = threadIdx.x; i < 4096; i += 256) {
    int r = i >> 6, c = i & 63;
    tile[r][c] = W[((size_t)h * 512 + d0 + r) * DH + t0 + c];
  }
  __syncthreads();
  for (int i = threadIdx.x; i < 4096; i += 256) {
    int tr = i >> 6, d = i & 63;
    out[((size_t)(h * DH + t0 + tr)) * 512 + d0 + d] = to_bf16(tile[d][tr]);
  }
}

// ---------------- batched projection GEMM (Q,K,V) ----------------
__global__ __launch_bounds__(256) void proj_gemm(const bf16* __restrict__ Qb, const bf16* __restrict__ Wqt,
                                                 const bf16* __restrict__ Kb, const bf16* __restrict__ Wkt,
                                                 const bf16* __restrict__ Vb, const bf16* __restrict__ Wvt,
                                                 bf16* __restrict__ qb, bf16* __restrict__ kb,
                                                 bf16* __restrict__ vT) {
  const int LD = 72;
  __shared__ bf16 As[64 * LD];
  __shared__ bf16 Bs[64 * LD];
  int b = blockIdx.x;
  const bf16 *A, *Bt;
  bf16* Cout;
  int N, m0, n0, tr;
  if (b < 512)       { A = Qb; Bt = Wqt; Cout = qb; N = 512;  m0 = (b >> 3) * 64; n0 = (b & 7) * 64;  tr = 0; }
  else if (b < 1024) { b -= 512;  A = Kb; Bt = Wkt; Cout = kb; N = 512;  m0 = (b >> 3) * 64; n0 = (b & 7) * 64;  tr = 0; }
  else               { b -= 1024; A = Vb; Bt = Wvt; Cout = vT; N = 1024; m0 = (b >> 4) * 64; n0 = (b & 15) * 64; tr = 1; }

  int tid = threadIdx.x;
  int lane = tid & 63, w = tid >> 6;
  int quad = lane >> 4, l16 = lane & 15;
  int wm = (w >> 1) * 32, wn = (w & 1) * 32;

  f32x4 acc[2][2] = {};
  for (int k0 = 0; k0 < 512; k0 += 64) {
    for (int i = tid; i < 64 * 8; i += 256) {
      int r = i >> 3, c = (i & 7) * 8;
      *(bf16x8*)&As[r * LD + c] = *(const bf16x8*)&A[(size_t)(m0 + r) * 512 + k0 + c];
      *(bf16x8*)&Bs[r * LD + c] = *(const bf16x8*)&Bt[(size_t)(n0 + r) * 512 + k0 + c];
    }
    __syncthreads();
#pragma unroll
    for (int kk = 0; kk < 2; kk++) {
      bf16x8 af[2], bfr[2];
#pragma unroll
      for (int i = 0; i < 2; i++)
        af[i] = *(const bf16x8*)&As[(wm + i * 16 + l16) * LD + kk * 32 + quad * 8];
#pragma unroll
      for (int j = 0; j < 2; j++)
        bfr[j] = *(const bf16x8*)&Bs[(wn + j * 16 + l16) * LD + kk * 32 + quad * 8];
#pragma unroll
      for (int i = 0; i < 2; i++)
#pragma unroll
        for (int j = 0; j < 2; j++)
          acc[i][j] = __builtin_amdgcn_mfma_f32_16x16x32_bf16(af[i], bfr[j], acc[i][j], 0, 0, 0);
    }
    __syncthreads();
  }
  if (!tr) {
#pragma unroll
    for (int i = 0; i < 2; i++)
#pragma unroll
      for (int j = 0; j < 2; j++)
#pragma unroll
        for (int r = 0; r < 4; r++)
          Cout[(size_t)(m0 + wm + i * 16 + quad * 4 + r) * N + n0 + wn + j * 16 + l16] =
              to_bf16(acc[i][j][r]);
  } else {
    bf16* tb = As;  // reuse As: [col 64][row 64], LD 72
#pragma unroll
    for (int i = 0; i < 2; i++)
#pragma unroll
      for (int j = 0; j < 2; j++)
#pragma unroll
        for (int r = 0; r < 4; r++)
          tb[(wn + j * 16 + l16) * LD + wm + i * 16 + quad * 4 + r] = to_bf16(acc[i][j][r]);
    __syncthreads();
    for (int idx = tid; idx < 512; idx += 256) {
      int c = idx >> 3, s = idx & 7;
      *(bf16x8*)&vT[(size_t)(n0 + c) * 4096 + m0 + s * 8] = *(const bf16x8*)&tb[c * LD + s * 8];
    }
  }
}

// ---------------- fused attention (no K/V LDS staging) ----------------
// qb,kb: [N][512]; vT: [1024][N]; x: [N][1024]
// Grid 512 = 2 blocks/CU: blk = qb64*8 + head*2 + half -> head fixed per XCD
// Block: 256 thr / 4 waves, 32 queries, all 4096 keys (64-key iters).
//   S : wave w computes q-tiles {0,1} x key-col tile w (16 keys). K frags direct
//       from global (B-layout rows = 16 x 64B segments, L2-resident).
//   PV: wave w owns q-tiles {0,1} x dv range w*64..+63; V frags direct from global.
//   P : only LDS traffic — double-buffered pt, ONE barrier per iter.
//   L : waves 0/1 accumulate ones-column MFMA for q-tile 0/1 (uniform branch).
__global__ __launch_bounds__(256, 2) void attn(const bf16* __restrict__ qb,
                                               const bf16* __restrict__ kb,
                                               const bf16* __restrict__ vT,
                                               bf16* __restrict__ x) {
  __shared__ __align__(16) bf16 pt[2][32 * 72];   // [q][key], +8 pad
  __shared__ float Lrow[32];

  const int head = (blockIdx.x >> 1) & 3;
  const int q0 = (blockIdx.x >> 3) * 64 + (blockIdx.x & 1) * 32;
  const int tid = threadIdx.x;
  const int lane = tid & 63, w = tid >> 6;       // 4 waves
  const int quad = lane >> 4, l16 = lane & 15;

  // all-ones B-fragment: B[n][k]=(n==0) -> D[q][0] = sum_k P[q][k]
  bf16x8 onesf;
  {
    union { bf16 h[8]; bf16x8 v; } u;
    bf16 one = to_bf16(1.0f), zero = to_bf16(0.0f);
#pragma unroll
    for (int j = 0; j < 8; j++) u.h[j] = (l16 == 0) ? one : zero;
    onesf = u.v;
  }

  // q fragments: rows i*16 (A-layout m=l16, k=quad*8+j)
  bf16x8 qf[2][4];
#pragma unroll
  for (int i = 0; i < 2; i++) {
    const bf16* qrow = &qb[(size_t)(q0 + i * 16 + l16) * 512 + head * 128];
#pragma unroll
    for (int kk = 0; kk < 4; kk++) qf[i][kk] = *(const bf16x8*)&qrow[kk * 32 + quad * 8];
  }

  // hoisted global bases (advance by 64 keys per iter)
  const bf16* kbase = &kb[(size_t)(w * 16 + l16) * 512 + head * 128 + quad * 8];
  const bf16* vbase[4];
#pragma unroll
  for (int c = 0; c < 4; c++)
    vbase[c] = &vT[(size_t)(head * 256 + w * 64 + c * 16 + l16) * 4096 + quad * 8];

  f32x4 oacc[2][4] = {};
  f32x4 oL = {};
  const float scale = 1.0f / 64.0f;  // 1/sqrt(4096)

  for (int it = 0; it < 64; it++) {
    const int key0 = it * 64;
    const int buf = it & 1;

    // ---- issue all global loads up front (K for S now, V for PV after barrier) ----
    bf16x8 kf[4], vf[2][4];
#pragma unroll
    for (int kk = 0; kk < 4; kk++)
      kf[kk] = *(const bf16x8*)&kbase[(size_t)key0 * 512 + kk * 32];
#pragma unroll
    for (int kk = 0; kk < 2; kk++)
#pragma unroll
      for (int c = 0; c < 4; c++)
        vf[kk][c] = *(const bf16x8*)&vbase[c][key0 + kk * 32];

    // ---- S: q-tiles 0,1 x key tile w ----
    f32x4 sacc[2] = {};
#pragma unroll
    for (int kk = 0; kk < 4; kk++) {
#pragma unroll
      for (int i = 0; i < 2; i++)
        sacc[i] = __builtin_amdgcn_mfma_f32_16x16x32_bf16(qf[i][kk], kf[kk], sacc[i], 0, 0, 0);
    }
#pragma unroll
    for (int i = 0; i < 2; i++)
#pragma unroll
      for (int r = 0; r < 4; r++)
        pt[buf][(i * 16 + quad * 4 + r) * 72 + w * 16 + l16] =
            to_bf16(__expf(sacc[i][r] * scale));
    __syncthreads();  // pt[buf] complete; prior buf's readers already barriered

    // ---- PV: q-tiles 0,1 x dv cols w*64..+63 ----
#pragma unroll
    for (int kk = 0; kk < 2; kk++) {
      bf16x8 pf[2];
#pragma unroll
      for (int i = 0; i < 2; i++)
        pf[i] = *(const bf16x8*)&pt[buf][(i * 16 + l16) * 72 + kk * 32 + quad * 8];
      if (w == 0)      oL = __builtin_amdgcn_mfma_f32_16x16x32_bf16(pf[0], onesf, oL, 0, 0, 0);
      else if (w == 1) oL = __builtin_amdgcn_mfma_f32_16x16x32_bf16(pf[1], onesf, oL, 0, 0, 0);
#pragma unroll
      for (int c = 0; c < 4; c++)
#pragma unroll
        for (int i = 0; i < 2; i++)
          oacc[i][c] = __builtin_amdgcn_mfma_f32_16x16x32_bf16(pf[i], vf[kk][c], oacc[i][c], 0, 0, 0);
    }
  }

  // L for q-tile w (waves 0,1) at lanes l16==0 (C-layout col 0)
  if (w < 2 && l16 == 0) {
#pragma unroll
    for (int r = 0; r < 4; r++) Lrow[w * 16 + quad * 4 + r] = oL[r];
  }
  __syncthreads();

  // normalize + write x[n][head*256 + w*64 + ...]
#pragma unroll
  for (int i = 0; i < 2; i++)
#pragma unroll
    for (int c = 0; c < 4; c++)
#pragma unroll
      for (int r = 0; r < 4; r++) {
        int row = i * 16 + quad * 4 + r;
        float v = oacc[i][c][r] / Lrow[row];
        x[(size_t)(q0 + row) * 1024 + head * 256 + w * 64 + c * 16 + l16] = to_bf16(v);
      }
}

// ---------------- output GEMM: out[M][512] = x[M][1024] @ Wob[512][1024]^T, fp32 out ----------------
__global__ __launch_bounds__(256) void out_gemm(const bf16* __restrict__ A,
                                                const bf16* __restrict__ Bt,
                                                float* __restrict__ C) {
  const int LD = 72;
  __shared__ bf16 As[64 * LD];
  __shared__ bf16 Bs[64 * LD];
  int tid = threadIdx.x;
  int lane = tid & 63, w = tid >> 6;
  int quad = lane >> 4, l16 = lane & 15;
  int wm = (w >> 1) * 32, wn = (w & 1) * 32;
  int m0 = blockIdx.x * 64, n0 = blockIdx.y * 64;

  f32x4 acc[2][2] = {};
  for (int k0 = 0; k0 < 1024; k0 += 64) {
    for (int i = tid; i < 64 * 8; i += 256) {
      int r = i >> 3, c = (i & 7) * 8;
      *(bf16x8*)&As[r * LD + c] = *(const bf16x8*)&A[(size_t)(m0 + r) * 1024 + k0 + c];
      *(bf16x8*)&Bs[r * LD + c] = *(const bf16x8*)&Bt[(size_t)(n0 + r) * 1024 + k0 + c];
    }
    __syncthreads();
#pragma unroll
    for (int kk = 0; kk < 2; kk++) {
      bf16x8 af[2], bfr[2];
#pragma unroll
      for (int i = 0; i < 2; i++)
        af[i] = *(const bf16x8*)&As[(wm + i * 16 + l16) * LD + kk * 32 + quad * 8];
#pragma unroll
      for (int j = 0; j < 2; j++)
        bfr[j] = *(const bf16x8*)&Bs[(wn + j * 16 + l16) * LD + kk * 32 + quad * 8];
#pragma unroll
      for (int i = 0; i < 2; i++)
#pragma unroll
        for (int j = 0; j < 2; j++)
          acc[i][j] = __builtin_amdgcn_mfma_f32_16x16x32_bf16(af[i], bfr[j], acc[i][j], 0, 0, 0);
    }
    __syncthreads();
  }
#pragma unroll
  for (int i = 0; i < 2; i++)
#pragma unroll
    for (int j = 0; j < 2; j++)
#pragma unroll
      for (int r = 0; r < 4; r++)
        C[(size_t)(m0 + wm + i * 16 + quad * 4 + r) * 512 + n0 + wn + j * 16 + l16] =
            acc[i][j][r];
}

// ---------------- launch ----------------
extern "C" void kernel_launch(void* const* d_in, const int* in_sizes, int n_in,
                              void* d_out, int out_size, void* d_ws, size_t ws_size,
                              hipStream_t stream) {
  const float* Q  = (const float*)d_in[0];
  const float* Km = (const float*)d_in[1];
  const float* V  = (const float*)d_in[2];
  const float* Wq = (const float*)d_in[3];
  const float* Wk = (const float*)d_in[4];
  const float* Wv = (const float*)d_in[5];
  const float* Wo = (const float*)d_in[6];
  float* out = (float*)d_out;

  bf16* ws  = (bf16*)d_ws;
  bf16* Qb  = ws;                 // 4096x512
  bf16* Kb  = Qb + 2097152;
  bf16* Vb  = Kb + 2097152;
  bf16* Wqt = Vb + 2097152;       // 512x512  (Bt)
  bf16* Wkt = Wqt + 262144;
  bf16* Wvt = Wkt + 262144;       // 1024x512 (Bt)
  bf16* Wob = Wvt + 524288;       // 512x1024 (Bt = Wo as-is)
  bf16* qb  = Wob + 524288;       // 4096x512
  bf16* kb  = qb + 2097152;
  bf16* vT  = kb + 2097152;       // 1024x4096
  bf16* x   = vT + 4194304;       // 4096x1024

  prep<<<3712, 256, 0, stream>>>(Q, Km, V, Wo, Wq, Wk, Wv, Qb, Kb, Vb, Wob, Wqt, Wkt, Wvt);
  proj_gemm<<<2048, 256, 0, stream>>>(Qb, Wqt, Kb, Wkt, Vb, Wvt, qb, kb, vT);
  attn<<<512, 256, 0, stream>>>(qb, kb, vT, x);
  out_gemm<<<dim3(64, 8), 256, 0, stream>>>(x, Wob, out);
}

// Round 6
// 300.230 us; speedup vs baseline: 1.0792x; 1.0003x over previous
//
#include <hip/hip_runtime.h>
#include <hip/hip_bf16.h>

typedef __hip_bfloat16 bf16;
typedef __attribute__((ext_vector_type(8))) short bf16x8;
typedef __attribute__((ext_vector_type(4))) float f32x4;

#define N_LOC 4096

__device__ __forceinline__ bf16 to_bf16(float f) { return __float2bfloat16(f); }

// ---------------- prep: f32->bf16 convert (Q,K,V,Wo) + W transpose-pack, one launch ----------------
__global__ __launch_bounds__(256) void prep(const float* __restrict__ Q, const float* __restrict__ K,
                                            const float* __restrict__ V, const float* __restrict__ Wo,
                                            const float* __restrict__ Wq, const float* __restrict__ Wk,
                                            const float* __restrict__ Wv,
                                            bf16* __restrict__ Qb, bf16* __restrict__ Kb,
                                            bf16* __restrict__ Vb, bf16* __restrict__ Wob,
                                            bf16* __restrict__ oq, bf16* __restrict__ ok,
                                            bf16* __restrict__ ov) {
  int b = blockIdx.x;
  if (b < 3328) {
    long i = ((long)b * 256 + threadIdx.x) * 8;
    const float* src; bf16* dst; long off;
    if (i < 2097152)      { src = Q;  dst = Qb;  off = i; }
    else if (i < 4194304) { src = K;  dst = Kb;  off = i - 2097152; }
    else if (i < 6291456) { src = V;  dst = Vb;  off = i - 4194304; }
    else                  { src = Wo; dst = Wob; off = i - 6291456; }
    float4 a = *(const float4*)&src[off];
    float4 c = *(const float4*)&src[off + 4];
    union { bf16 h[8]; bf16x8 v; } u;
    u.h[0] = to_bf16(a.x); u.h[1] = to_bf16(a.y); u.h[2] = to_bf16(a.z); u.h[3] = to_bf16(a.w);
    u.h[4] = to_bf16(c.x); u.h[5] = to_bf16(c.y); u.h[6] = to_bf16(c.z); u.h[7] = to_bf16(c.w);
    *(bf16x8*)&dst[off] = u.v;
    return;
  }
  int t = b - 3328;
  int z = t >> 7, rem = t & 127;
  int xb = rem & 7, y = rem >> 3;
  const float* W = (z == 0) ? Wq : (z == 1) ? Wk : Wv;
  bf16* out = (z == 0) ? oq : (z == 1) ? ok : ov;
  int DH = (z == 2) ? 256 : 128;
  int nt = DH >> 6;
  if (y >= 4 * nt) return;
  int h = y / nt, tt = y - h * nt;
  int d0 = xb * 64, t0 = tt * 64;
  __shared__ float tile[64][65];
  for (int i = threadIdx.x; i < 4096; i += 256) {
    int r = i >> 6, c = i & 63;
    tile[r][c] = W[((size_t)h * 512 + d0 + r) * DH + t0 + c];
  }
  __syncthreads();
  for (int i = threadIdx.x; i < 4096; i += 256) {
    int tr = i >> 6, d = i & 63;
    out[((size_t)(h * DH + t0 + tr)) * 512 + d0 + d] = to_bf16(tile[d][tr]);
  }
}

// ---------------- batched projection GEMM (Q,K,V) ----------------
__global__ __launch_bounds__(256) void proj_gemm(const bf16* __restrict__ Qb, const bf16* __restrict__ Wqt,
                                                 const bf16* __restrict__ Kb, const bf16* __restrict__ Wkt,
                                                 const bf16* __restrict__ Vb, const bf16* __restrict__ Wvt,
                                                 bf16* __restrict__ qb, bf16* __restrict__ kb,
                                                 bf16* __restrict__ vT) {
  const int LD = 72;
  __shared__ bf16 As[64 * LD];
  __shared__ bf16 Bs[64 * LD];
  int b = blockIdx.x;
  const bf16 *A, *Bt;
  bf16* Cout;
  int N, m0, n0, tr;
  if (b < 512)       { A = Qb; Bt = Wqt; Cout = qb; N = 512;  m0 = (b >> 3) * 64; n0 = (b & 7) * 64;  tr = 0; }
  else if (b < 1024) { b -= 512;  A = Kb; Bt = Wkt; Cout = kb; N = 512;  m0 = (b >> 3) * 64; n0 = (b & 7) * 64;  tr = 0; }
  else               { b -= 1024; A = Vb; Bt = Wvt; Cout = vT; N = 1024; m0 = (b >> 4) * 64; n0 = (b & 15) * 64; tr = 1; }

  int tid = threadIdx.x;
  int lane = tid & 63, w = tid >> 6;
  int quad = lane >> 4, l16 = lane & 15;
  int wm = (w >> 1) * 32, wn = (w & 1) * 32;

  f32x4 acc[2][2] = {};
  for (int k0 = 0; k0 < 512; k0 += 64) {
    for (int i = tid; i < 64 * 8; i += 256) {
      int r = i >> 3, c = (i & 7) * 8;
      *(bf16x8*)&As[r * LD + c] = *(const bf16x8*)&A[(size_t)(m0 + r) * 512 + k0 + c];
      *(bf16x8*)&Bs[r * LD + c] = *(const bf16x8*)&Bt[(size_t)(n0 + r) * 512 + k0 + c];
    }
    __syncthreads();
#pragma unroll
    for (int kk = 0; kk < 2; kk++) {
      bf16x8 af[2], bfr[2];
#pragma unroll
      for (int i = 0; i < 2; i++)
        af[i] = *(const bf16x8*)&As[(wm + i * 16 + l16) * LD + kk * 32 + quad * 8];
#pragma unroll
      for (int j = 0; j < 2; j++)
        bfr[j] = *(const bf16x8*)&Bs[(wn + j * 16 + l16) * LD + kk * 32 + quad * 8];
#pragma unroll
      for (int i = 0; i < 2; i++)
#pragma unroll
        for (int j = 0; j < 2; j++)
          acc[i][j] = __builtin_amdgcn_mfma_f32_16x16x32_bf16(af[i], bfr[j], acc[i][j], 0, 0, 0);
    }
    __syncthreads();
  }
  if (!tr) {
#pragma unroll
    for (int i = 0; i < 2; i++)
#pragma unroll
      for (int j = 0; j < 2; j++)
#pragma unroll
        for (int r = 0; r < 4; r++)
          Cout[(size_t)(m0 + wm + i * 16 + quad * 4 + r) * N + n0 + wn + j * 16 + l16] =
              to_bf16(acc[i][j][r]);
  } else {
    bf16* tb = As;  // reuse As: [col 64][row 64], LD 72
#pragma unroll
    for (int i = 0; i < 2; i++)
#pragma unroll
      for (int j = 0; j < 2; j++)
#pragma unroll
        for (int r = 0; r < 4; r++)
          tb[(wn + j * 16 + l16) * LD + wm + i * 16 + quad * 4 + r] = to_bf16(acc[i][j][r]);
    __syncthreads();
    for (int idx = tid; idx < 512; idx += 256) {
      int c = idx >> 3, s = idx & 7;
      *(bf16x8*)&vT[(size_t)(n0 + c) * 4096 + m0 + s * 8] = *(const bf16x8*)&tb[c * LD + s * 8];
    }
  }
}

// ---------------- fused attention (direct-from-global K/V + 1-iter register prefetch) ----------------
// qb,kb: [N][512]; vT: [1024][N]; x: [N][1024]
// Grid 512 = 2 blocks/CU; block 256 thr / 4 waves, 32 queries, 64-key iters.
// Round-5 failure: loads issued and consumed in the SAME iter -> every iter pays
// full L2/L3 latency with only 2 waves/SIMD (MfmaUtil 11%, VALU 10%, all idle).
// Fix: kf/vf double-buffered in REGISTERS, prefetched one iter ahead. Buffer
// index is compile-time (2x-unrolled loop via macro) to avoid scratch spill.
// Final prefetch (it=64) reads ~64KB past kb/vT into adjacent ws arrays: unused, harmless.
__global__ __launch_bounds__(256, 2) void attn(const bf16* __restrict__ qb,
                                               const bf16* __restrict__ kb,
                                               const bf16* __restrict__ vT,
                                               bf16* __restrict__ x) {
  __shared__ __align__(16) bf16 pt[2][32 * 72];   // [q][key], +8 pad
  __shared__ float Lrow[32];

  const int head = (blockIdx.x >> 1) & 3;
  const int q0 = (blockIdx.x >> 3) * 64 + (blockIdx.x & 1) * 32;
  const int tid = threadIdx.x;
  const int lane = tid & 63, w = tid >> 6;       // 4 waves
  const int quad = lane >> 4, l16 = lane & 15;

  // all-ones B-fragment: B[n][k]=(n==0) -> D[q][0] = sum_k P[q][k]
  bf16x8 onesf;
  {
    union { bf16 h[8]; bf16x8 v; } u;
    bf16 one = to_bf16(1.0f), zero = to_bf16(0.0f);
#pragma unroll
    for (int j = 0; j < 8; j++) u.h[j] = (l16 == 0) ? one : zero;
    onesf = u.v;
  }

  // q fragments: rows i*16 (A-layout m=l16, k=quad*8+j)
  bf16x8 qf[2][4];
#pragma unroll
  for (int i = 0; i < 2; i++) {
    const bf16* qrow = &qb[(size_t)(q0 + i * 16 + l16) * 512 + head * 128];
#pragma unroll
    for (int kk = 0; kk < 4; kk++) qf[i][kk] = *(const bf16x8*)&qrow[kk * 32 + quad * 8];
  }

  // hoisted global bases (advance by 64 keys per iter)
  const bf16* kbase = &kb[(size_t)(w * 16 + l16) * 512 + head * 128 + quad * 8];
  const bf16* vbase[4];
#pragma unroll
  for (int c = 0; c < 4; c++)
    vbase[c] = &vT[(size_t)(head * 256 + w * 64 + c * 16 + l16) * 4096 + quad * 8];

  f32x4 oacc[2][4] = {};
  f32x4 oL = {};
  const float scale = 1.0f / 64.0f;  // 1/sqrt(4096)

  bf16x8 kf[2][4], vf[2][2][4];      // double-buffered fragment registers

#define LOAD_FRAGS(B, KEY0)                                                        \
  {                                                                                \
    const size_t key0_ = (KEY0);                                                   \
    _Pragma("unroll") for (int kk = 0; kk < 4; kk++)                               \
        kf[B][kk] = *(const bf16x8*)&kbase[key0_ * 512 + kk * 32];                 \
    _Pragma("unroll") for (int kk = 0; kk < 2; kk++)                               \
        _Pragma("unroll") for (int c = 0; c < 4; c++)                              \
            vf[B][kk][c] = *(const bf16x8*)&vbase[c][key0_ + kk * 32];             \
  }

#define STEP(CUR, NXT, IT)                                                         \
  {                                                                                \
    LOAD_FRAGS(NXT, ((IT) + 1) * 64);  /* prefetch next iter */                    \
    f32x4 sacc[2] = {};                                                            \
    _Pragma("unroll") for (int kk = 0; kk < 4; kk++) {                             \
      _Pragma("unroll") for (int i = 0; i < 2; i++)                                \
          sacc[i] = __builtin_amdgcn_mfma_f32_16x16x32_bf16(qf[i][kk], kf[CUR][kk],\
                                                            sacc[i], 0, 0, 0);     \
    }                                                                              \
    _Pragma("unroll") for (int i = 0; i < 2; i++)                                  \
        _Pragma("unroll") for (int r = 0; r < 4; r++)                              \
            pt[CUR][(i * 16 + quad * 4 + r) * 72 + w * 16 + l16] =                 \
                to_bf16(__expf(sacc[i][r] * scale));                               \
    __syncthreads();                                                               \
    _Pragma("unroll") for (int kk = 0; kk < 2; kk++) {                             \
      bf16x8 pf[2];                                                                \
      _Pragma("unroll") for (int i = 0; i < 2; i++)                                \
          pf[i] = *(const bf16x8*)&pt[CUR][(i * 16 + l16) * 72 + kk * 32 + quad * 8]; \
      if (w == 0)                                                                  \
        oL = __builtin_amdgcn_mfma_f32_16x16x32_bf16(pf[0], onesf, oL, 0, 0, 0);   \
      else if (w == 1)                                                             \
        oL = __builtin_amdgcn_mfma_f32_16x16x32_bf16(pf[1], onesf, oL, 0, 0, 0);   \
      _Pragma("unroll") for (int c = 0; c < 4; c++)                                \
          _Pragma("unroll") for (int i = 0; i < 2; i++)                            \
              oacc[i][c] = __builtin_amdgcn_mfma_f32_16x16x32_bf16(                \
                  pf[i], vf[CUR][kk][c], oacc[i][c], 0, 0, 0);                     \
    }                                                                              \
  }

  LOAD_FRAGS(0, 0);  // preload iter 0
  for (int it2 = 0; it2 < 32; it2++) {
    STEP(0, 1, it2 * 2);
    STEP(1, 0, it2 * 2 + 1);
  }
#undef STEP
#undef LOAD_FRAGS

  // L for q-tile w (waves 0,1) at lanes l16==0 (C-layout col 0)
  if (w < 2 && l16 == 0) {
#pragma unroll
    for (int r = 0; r < 4; r++) Lrow[w * 16 + quad * 4 + r] = oL[r];
  }
  __syncthreads();

  // normalize + write x[n][head*256 + w*64 + ...]
#pragma unroll
  for (int i = 0; i < 2; i++)
#pragma unroll
    for (int c = 0; c < 4; c++)
#pragma unroll
      for (int r = 0; r < 4; r++) {
        int row = i * 16 + quad * 4 + r;
        float v = oacc[i][c][r] / Lrow[row];
        x[(size_t)(q0 + row) * 1024 + head * 256 + w * 64 + c * 16 + l16] = to_bf16(v);
      }
}

// ---------------- output GEMM: out[M][512] = x[M][1024] @ Wob[512][1024]^T, fp32 out ----------------
__global__ __launch_bounds__(256) void out_gemm(const bf16* __restrict__ A,
                                                const bf16* __restrict__ Bt,
                                                float* __restrict__ C) {
  const int LD = 72;
  __shared__ bf16 As[64 * LD];
  __shared__ bf16 Bs[64 * LD];
  int tid = threadIdx.x;
  int lane = tid & 63, w = tid >> 6;
  int quad = lane >> 4, l16 = lane & 15;
  int wm = (w >> 1) * 32, wn = (w & 1) * 32;
  int m0 = blockIdx.x * 64, n0 = blockIdx.y * 64;

  f32x4 acc[2][2] = {};
  for (int k0 = 0; k0 < 1024; k0 += 64) {
    for (int i = tid; i < 64 * 8; i += 256) {
      int r = i >> 3, c = (i & 7) * 8;
      *(bf16x8*)&As[r * LD + c] = *(const bf16x8*)&A[(size_t)(m0 + r) * 1024 + k0 + c];
      *(bf16x8*)&Bs[r * LD + c] = *(const bf16x8*)&Bt[(size_t)(n0 + r) * 1024 + k0 + c];
    }
    __syncthreads();
#pragma unroll
    for (int kk = 0; kk < 2; kk++) {
      bf16x8 af[2], bfr[2];
#pragma unroll
      for (int i = 0; i < 2; i++)
        af[i] = *(const bf16x8*)&As[(wm + i * 16 + l16) * LD + kk * 32 + quad * 8];
#pragma unroll
      for (int j = 0; j < 2; j++)
        bfr[j] = *(const bf16x8*)&Bs[(wn + j * 16 + l16) * LD + kk * 32 + quad * 8];
#pragma unroll
      for (int i = 0; i < 2; i++)
#pragma unroll
        for (int j = 0; j < 2; j++)
          acc[i][j] = __builtin_amdgcn_mfma_f32_16x16x32_bf16(af[i], bfr[j], acc[i][j], 0, 0, 0);
    }
    __syncthreads();
  }
#pragma unroll
  for (int i = 0; i < 2; i++)
#pragma unroll
    for (int j = 0; j < 2; j++)
#pragma unroll
      for (int r = 0; r < 4; r++)
        C[(size_t)(m0 + wm + i * 16 + quad * 4 + r) * 512 + n0 + wn + j * 16 + l16] =
            acc[i][j][r];
}

// ---------------- launch ----------------
extern "C" void kernel_launch(void* const* d_in, const int* in_sizes, int n_in,
                              void* d_out, int out_size, void* d_ws, size_t ws_size,
                              hipStream_t stream) {
  const float* Q  = (const float*)d_in[0];
  const float* Km = (const float*)d_in[1];
  const float* V  = (const float*)d_in[2];
  const float* Wq = (const float*)d_in[3];
  const float* Wk = (const float*)d_in[4];
  const float* Wv = (const float*)d_in[5];
  const float* Wo = (const float*)d_in[6];
  float* out = (float*)d_out;

  bf16* ws  = (bf16*)d_ws;
  bf16* Qb  = ws;                 // 4096x512
  bf16* Kb  = Qb + 2097152;
  bf16* Vb  = Kb + 2097152;
  bf16* Wqt = Vb + 2097152;       // 512x512  (Bt)
  bf16* Wkt = Wqt + 262144;
  bf16* Wvt = Wkt + 262144;       // 1024x512 (Bt)
  bf16* Wob = Wvt + 524288;       // 512x1024 (Bt = Wo as-is)
  bf16* qb  = Wob + 524288;       // 4096x512
  bf16* kb  = qb + 2097152;
  bf16* vT  = kb + 2097152;       // 1024x4096
  bf16* x   = vT + 4194304;       // 4096x1024

  prep<<<3712, 256, 0, stream>>>(Q, Km, V, Wo, Wq, Wk, Wv, Qb, Kb, Vb, Wob, Wqt, Wkt, Wvt);
  proj_gemm<<<2048, 256, 0, stream>>>(Qb, Wqt, Kb, Wkt, Vb, Wvt, qb, kb, vT);
  attn<<<512, 256, 0, stream>>>(qb, kb, vT, x);
  out_gemm<<<dim3(64, 8), 256, 0, stream>>>(x, Wob, out);
}